// Round 7
// baseline (471.084 us; speedup 1.0000x reference)
//
#include <hip/hip_runtime.h>

// ---------------------------------------------------------------------------
// GraphSAGE (3x SAGEConv mean-agg + BN/ReLU) + link decoder.
// R7 changes vs R6:
//  - mm: 2-phase double-buffered pipeline (stage(s+1) issued BEFORE compute(s),
//    one vmcnt(0)+barrier per K-step) -> staging latency hidden under MFMA.
//    Col-split into 2 blocks (64KB LDS, 2 blocks/CU) with bid swizzle so the
//    A-sharing pair is adjacent (A re-read hits L2).
//  - agg: UNCHANGED (proven BW-bound at ~6.4 TB/s logical; R5 vs R6 equal).
// ---------------------------------------------------------------------------

typedef unsigned int uint;
using s16x8 = __attribute__((ext_vector_type(8))) short;
using f32x4 = __attribute__((ext_vector_type(4))) float;

__device__ inline void bsplit(float v, ushort& hi, ushort& lo) {
    // round-to-nearest-even bf16 split: v ~= hi + lo to ~2^-17 rel
    uint u = __float_as_uint(v);
    uint hb = (u + 0x7FFFu + ((u >> 16) & 1u)) >> 16;
    hi = (ushort)hb;
    float r = v - __uint_as_float(hb << 16);
    uint u2 = __float_as_uint(r);
    lo = (ushort)((u2 + 0x7FFFu + ((u2 >> 16) & 1u)) >> 16);
}

// swizzle a ushort index within its 64-ushort K-slice: chunk ^= (row&7)
__device__ inline uint swz(uint i, uint r) {
    return (i & ~63u) | ((i ^ (r << 3)) & 56u) | (i & 7u);
}

// async global->LDS, 16 bytes per lane
__device__ inline void gload16(const void* g, void* l) {
    __builtin_amdgcn_global_load_lds(
        (const __attribute__((address_space(1))) unsigned int*)g,
        (__attribute__((address_space(3))) unsigned int*)l, 16, 0, 0);
}

// ---------------- CSR build ----------------
__global__ void count_kernel(const int* __restrict__ dst, int* __restrict__ cnt, int E) {
    int i = blockIdx.x * blockDim.x + threadIdx.x;
    if (i < E) atomicAdd(&cnt[dst[i]], 1);
}

__global__ void scanA_kernel(const int* __restrict__ cnt, int* __restrict__ ptr,
                             int* __restrict__ tilesum, int n) {
    __shared__ int sd[1024];
    int t = threadIdx.x;
    int i = blockIdx.x * 1024 + t;
    int v = (i < n) ? cnt[i] : 0;
    sd[t] = v;
    __syncthreads();
    #pragma unroll
    for (int off = 1; off < 1024; off <<= 1) {
        int add = (t >= off) ? sd[t - off] : 0;
        __syncthreads();
        sd[t] += add;
        __syncthreads();
    }
    if (i < n) ptr[i] = sd[t] - v;              // local exclusive
    if (t == 1023) tilesum[blockIdx.x] = sd[t]; // tile total
}

__global__ void scanB_kernel(int* __restrict__ tilesum, int* __restrict__ ptr,
                             int ntiles, int n) {
    if (threadIdx.x == 0 && blockIdx.x == 0) {
        int running = 0;
        for (int b = 0; b < ntiles; ++b) {
            int t = tilesum[b];
            tilesum[b] = running;
            running += t;
        }
        ptr[n] = running;
    }
}

__global__ void scanC_kernel(int* __restrict__ ptr, const int* __restrict__ tilesum, int n) {
    int i = blockIdx.x * blockDim.x + threadIdx.x;
    if (i < n) ptr[i] += tilesum[i >> 10];
}

__global__ void scatter_kernel(const int* __restrict__ src, const int* __restrict__ dst,
                               const int* __restrict__ ptr, int* __restrict__ cursor,
                               int* __restrict__ edges, int E) {
    int i = blockIdx.x * blockDim.x + threadIdx.x;
    if (i < E) {
        int d = dst[i];
        int pos = ptr[d] + atomicAdd(&cursor[d], 1);
        edges[pos] = src[i];
    }
}

// ---------------- conversions (pre-swizzled stores) ----------------
// A row (K=256): [hi(0..255) | lo(0..255)] (KP=512), chunk-swizzled per slice
__global__ __launch_bounds__(256) void convx_kernel(const float* __restrict__ x,
                                                    ushort* __restrict__ A3, int total) {
    int e = blockIdx.x * 256 + threadIdx.x;   // total = N*64 (float4 groups)
    if (e >= total) return;
    uint row = e >> 6;
    uint k4 = (e & 63) << 2;
    float4 v = *(const float4*)(x + (size_t)row * 256 + k4);
    ushort4 hi, lo;
    bsplit(v.x, hi.x, lo.x); bsplit(v.y, hi.y, lo.y);
    bsplit(v.z, hi.z, lo.z); bsplit(v.w, hi.w, lo.w);
    ushort* d = A3 + (size_t)row * 512;
    *(ushort4*)(d + swz(k4, row))       = hi;
    *(ushort4*)(d + swz(k4 + 256, row)) = lo;
}

// WS[n][k'] n-major, k' = [Wh | Wlo | Wh], chunk-swizzled per slice
__global__ void wprep_all_kernel(
    const float* __restrict__ w1l, const float* __restrict__ w1r,
    const float* __restrict__ w2l, const float* __restrict__ w2r,
    const float* __restrict__ w3l, const float* __restrict__ w3r,
    const float* __restrict__ dw1,
    ushort* __restrict__ WS1, ushort* __restrict__ WS2,
    ushort* __restrict__ WS3, ushort* __restrict__ WS4)
{
    int which = blockIdx.y;
    uint n = blockIdx.x;
    uint k = threadIdx.x;
    const float *wa, *wb;
    uint K, lda, aoff, boff;
    ushort* WS;
    switch (which) {
        case 0:  wa = w1l; wb = w1r; K = 256; lda = 256; aoff = 0; boff = 0;   WS = WS1; break;
        case 1:  wa = w2l; wb = w2r; K = 128; lda = 128; aoff = 0; boff = 0;   WS = WS2; break;
        case 2:  wa = w3l; wb = w3r; K = 128; lda = 128; aoff = 0; boff = 0;   WS = WS3; break;
        default: wa = dw1; wb = dw1; K = 128; lda = 256; aoff = 0; boff = 128; WS = WS4; break;
    }
    if (k >= K) return;
    const float* srcr = (n < 128) ? (wa + (size_t)n * lda + aoff)
                                  : (wb + (size_t)(n - 128) * lda + boff);
    ushort hi, lo;
    bsplit(srcr[k], hi, lo);
    ushort* d = WS + (size_t)n * 3 * K;
    d[swz(k, n)]         = hi;
    d[swz(K + k, n)]     = lo;
    d[swz(2 * K + k, n)] = hi;
}

// ---------------- MFMA GEMM (2-phase double-buffered) ----------------
// Block = 128 rows x 128 cols (col half selected by bid&1). 4 waves, 64x64.
// A[M][KP] = [hi|lo] pre-swizzled; W[256][KP*3/2] = [Wh|Wlo|Wh] pre-swizzled.
// Staging = global_load_lds 16B into LINEAR LDS; ds_read applies the XOR.
// Pipeline: stage(s+1) issued BEFORE compute(s); vmcnt(0)+barrier per step.
template <int KP>
__global__ __launch_bounds__(256, 2) void mm_kernel(const ushort* __restrict__ A,
                                                    const ushort* __restrict__ WS,
                                                    float* __restrict__ Cl,
                                                    float* __restrict__ Cr, int M) {
    constexpr int KS  = (KP / 64) + (KP / 128);   // 12 (KP=512) or 6 (KP=256)
    constexpr int WKP = KP + KP / 2;
    __shared__ ushort At[2][128 * 64];
    __shared__ ushort Bt[2][128 * 64];
    const int t = threadIdx.x;
    const int lane = t & 63;
    const int wave = t >> 6;
    const int wm = wave >> 1, wn = wave & 1;      // 2x2 waves, 64x64 each
    const int bid = blockIdx.x;
    const int row0 = (bid >> 1) * 128;            // paired col-blocks adjacent
    const int n0 = (bid & 1) * 128;               // column half
    const int l15 = lane & 15;
    const int l4 = lane >> 4;
    const int l8 = lane >> 3;                     // staging row within 8-row group
    const int c8 = lane & 7;                      // staging chunk within row

    f32x4 acc[4][4] = {};

    #define STAGE(s_, b_)                                                       \
    {                                                                           \
        const int as_ = ((s_) < KP / 128) ? (s_) : (s_) - (KP / 128);           \
        _Pragma("unroll")                                                       \
        for (int j = 0; j < 4; ++j) {                                           \
            int jj = wave + j * 4;                                              \
            int r = jj * 8 + l8;                                                \
            gload16(A + (size_t)(row0 + r) * KP + as_ * 64 + c8 * 8,            \
                    (char*)At[b_] + jj * 1024 + lane * 16);                     \
        }                                                                       \
        _Pragma("unroll")                                                       \
        for (int j = 0; j < 4; ++j) {                                           \
            int jj = wave + j * 4;                                              \
            int r = jj * 8 + l8;                                                \
            gload16(WS + (size_t)(n0 + r) * WKP + (s_) * 64 + c8 * 8,           \
                    (char*)Bt[b_] + jj * 1024 + lane * 16);                     \
        }                                                                       \
    }

    STAGE(0, 0);
    asm volatile("s_waitcnt vmcnt(0)" ::: "memory");
    __syncthreads();

    for (int s = 0; s < KS; ++s) {
        const int buf = s & 1;
        if (s + 1 < KS) STAGE(s + 1, buf ^ 1);    // prefetch flies under MFMA
        #pragma unroll
        for (int kk = 0; kk < 64; kk += 32) {
            s16x8 af[4], bf[4];
            #pragma unroll
            for (int mi = 0; mi < 4; ++mi) {
                int r = wm * 64 + mi * 16 + l15;
                int off = (kk + l4 * 8) ^ ((r & 7) * 8);
                af[mi] = *(const s16x8*)&At[buf][r * 64 + off];
            }
            #pragma unroll
            for (int ni = 0; ni < 4; ++ni) {
                int r = wn * 64 + ni * 16 + l15;
                int off = (kk + l4 * 8) ^ ((r & 7) * 8);
                bf[ni] = *(const s16x8*)&Bt[buf][r * 64 + off];
            }
            #pragma unroll
            for (int mi = 0; mi < 4; ++mi)
                #pragma unroll
                for (int ni = 0; ni < 4; ++ni)
                    acc[mi][ni] = __builtin_amdgcn_mfma_f32_16x16x32_bf16(
                        af[mi], bf[ni], acc[mi][ni], 0, 0, 0);
        }
        asm volatile("s_waitcnt vmcnt(0)" ::: "memory");
        __syncthreads();
    }
    #undef STAGE

    // ---- epilogue: row = (lane>>4)*4+j, col = lane&15 within 16x16
    float* base = (n0 == 0) ? Cl : Cr;
    #pragma unroll
    for (int mi = 0; mi < 4; ++mi) {
        int rbase = row0 + wm * 64 + mi * 16 + l4 * 4;
        #pragma unroll
        for (int ni = 0; ni < 4; ++ni) {
            int col = wn * 64 + ni * 16 + l15;
            #pragma unroll
            for (int j = 0; j < 4; ++j) {
                int r = rbase + j;
                if (r < M) base[(size_t)r * 128 + col] = acc[mi][ni][j];
            }
        }
    }
}

// ---------------- aggregation ----------------
// One node per wave: lanes 0-31 even edge slots, 32-63 odd; shfl_xor combine.
// out = opt_bn_relu( mean tl[src] + bl + tr[i] ), emits h[n][256]=[hi|lo] swz.
__global__ __launch_bounds__(256, 4) void agg_kernel(
    const float* __restrict__ tl, const float* __restrict__ tr,
    const int* __restrict__ ptr, const int* __restrict__ edges,
    const float* __restrict__ bl,
    const float* __restrict__ bng, const float* __restrict__ bnb,
    const float* __restrict__ bnm, const float* __restrict__ bnv,
    int do_bn, ushort* __restrict__ h3, int n) {
    const int wave = threadIdx.x >> 6;
    const int lane = threadIdx.x & 63;
    const uint node = blockIdx.x * 4 + wave;
    if (node >= (uint)n) return;
    const int half = lane >> 5;
    const uint q4 = (lane & 31) << 2;             // 4 feats per lane
    const int p0 = ptr[node], p1 = ptr[node + 1];
    float4 a0 = make_float4(0.f, 0.f, 0.f, 0.f), a1 = a0, a2 = a0, a3 = a0;
    float4 a4 = a0, a5 = a0, a6 = a0, a7 = a0;
    int e = p0 + half;
    for (; e + 14 < p1; e += 16) {                // 8 edges per half per iter
        int i0 = edges[e],      i1 = edges[e + 2],  i2 = edges[e + 4],  i3 = edges[e + 6];
        int i4 = edges[e + 8],  i5 = edges[e + 10], i6 = edges[e + 12], i7 = edges[e + 14];
        float4 v0 = *(const float4*)(tl + (size_t)i0 * 128 + q4);
        float4 v1 = *(const float4*)(tl + (size_t)i1 * 128 + q4);
        float4 v2 = *(const float4*)(tl + (size_t)i2 * 128 + q4);
        float4 v3 = *(const float4*)(tl + (size_t)i3 * 128 + q4);
        float4 v4 = *(const float4*)(tl + (size_t)i4 * 128 + q4);
        float4 v5 = *(const float4*)(tl + (size_t)i5 * 128 + q4);
        float4 v6 = *(const float4*)(tl + (size_t)i6 * 128 + q4);
        float4 v7 = *(const float4*)(tl + (size_t)i7 * 128 + q4);
        a0.x += v0.x; a0.y += v0.y; a0.z += v0.z; a0.w += v0.w;
        a1.x += v1.x; a1.y += v1.y; a1.z += v1.z; a1.w += v1.w;
        a2.x += v2.x; a2.y += v2.y; a2.z += v2.z; a2.w += v2.w;
        a3.x += v3.x; a3.y += v3.y; a3.z += v3.z; a3.w += v3.w;
        a4.x += v4.x; a4.y += v4.y; a4.z += v4.z; a4.w += v4.w;
        a5.x += v5.x; a5.y += v5.y; a5.z += v5.z; a5.w += v5.w;
        a6.x += v6.x; a6.y += v6.y; a6.z += v6.z; a6.w += v6.w;
        a7.x += v7.x; a7.y += v7.y; a7.z += v7.z; a7.w += v7.w;
    }
    for (; e < p1; e += 2) {
        int i0 = edges[e];
        float4 v0 = *(const float4*)(tl + (size_t)i0 * 128 + q4);
        a0.x += v0.x; a0.y += v0.y; a0.z += v0.z; a0.w += v0.w;
    }
    float4 s;
    s.x = ((a0.x + a1.x) + (a2.x + a3.x)) + ((a4.x + a5.x) + (a6.x + a7.x));
    s.y = ((a0.y + a1.y) + (a2.y + a3.y)) + ((a4.y + a5.y) + (a6.y + a7.y));
    s.z = ((a0.z + a1.z) + (a2.z + a3.z)) + ((a4.z + a5.z) + (a6.z + a7.z));
    s.w = ((a0.w + a1.w) + (a2.w + a3.w)) + ((a4.w + a5.w) + (a6.w + a7.w));
    // combine even/odd halves (lane <-> lane^32)
    s.x += __shfl_xor(s.x, 32);
    s.y += __shfl_xor(s.y, 32);
    s.z += __shfl_xor(s.z, 32);
    s.w += __shfl_xor(s.w, 32);
    if (half == 0) {
        float inv = 1.f / fmaxf((float)(p1 - p0), 1.f);
        float4 r = *(const float4*)(tr + (size_t)node * 128 + q4);
        float4 b = *(const float4*)(bl + q4);
        float4 val;
        val.x = fmaf(s.x, inv, b.x) + r.x;
        val.y = fmaf(s.y, inv, b.y) + r.y;
        val.z = fmaf(s.z, inv, b.z) + r.z;
        val.w = fmaf(s.w, inv, b.w) + r.w;
        if (do_bn) {
            float4 g = *(const float4*)(bng + q4);
            float4 be = *(const float4*)(bnb + q4);
            float4 m = *(const float4*)(bnm + q4);
            float4 vv = *(const float4*)(bnv + q4);
            val.x = fmaxf(fmaf(val.x - m.x, g.x * rsqrtf(vv.x + 1e-5f), be.x), 0.f);
            val.y = fmaxf(fmaf(val.y - m.y, g.y * rsqrtf(vv.y + 1e-5f), be.y), 0.f);
            val.z = fmaxf(fmaf(val.z - m.z, g.z * rsqrtf(vv.z + 1e-5f), be.z), 0.f);
            val.w = fmaxf(fmaf(val.w - m.w, g.w * rsqrtf(vv.w + 1e-5f), be.w), 0.f);
        }
        ushort4 hi, lo;
        bsplit(val.x, hi.x, lo.x); bsplit(val.y, hi.y, lo.y);
        bsplit(val.z, hi.z, lo.z); bsplit(val.w, hi.w, lo.w);
        ushort* d = h3 + (size_t)node * 256;
        *(ushort4*)(d + swz(q4, node))       = hi;
        *(ushort4*)(d + swz(q4 + 128, node)) = lo;
    }
}

// ---------------- decoder: relu(u[s] + v[d] + b) . w2 + b2 ----------------
__global__ __launch_bounds__(256) void decode_kernel(
    const float* __restrict__ u, const float* __restrict__ v,
    const int* __restrict__ eli, const float* __restrict__ db1,
    const float* __restrict__ dw2, const float* __restrict__ db2,
    float* __restrict__ out, int L) {
    __shared__ float sb[128], sw[128];
    if (threadIdx.x < 128) {
        sb[threadIdx.x] = db1[threadIdx.x];
        sw[threadIdx.x] = dw2[threadIdx.x];
    }
    __syncthreads();
    int p = blockIdx.x * 256 + threadIdx.x;
    if (p >= L) return;
    int s = eli[p], d = eli[L + p];
    const float* up = u + (size_t)s * 128;
    const float* vp = v + (size_t)d * 128;
    float acc = db2[0];
    #pragma unroll 8
    for (int o = 0; o < 128; o += 4) {
        float4 a = *(const float4*)(up + o);
        float4 b = *(const float4*)(vp + o);
        float4 bb = *(const float4*)(&sb[o]);
        float4 w = *(const float4*)(&sw[o]);
        acc += fmaxf(a.x + b.x + bb.x, 0.f) * w.x;
        acc += fmaxf(a.y + b.y + bb.y, 0.f) * w.y;
        acc += fmaxf(a.z + b.z + bb.z, 0.f) * w.z;
        acc += fmaxf(a.w + b.w + bb.w, 0.f) * w.w;
    }
    out[p] = acc;
}

extern "C" void kernel_launch(void* const* d_in, const int* in_sizes, int n_in,
                              void* d_out, int out_size, void* d_ws, size_t ws_size,
                              hipStream_t stream) {
    const float* x    = (const float*)d_in[0];
    const int*   ei   = (const int*)d_in[1];
    const int*   eli  = (const int*)d_in[2];
    const float* w1l  = (const float*)d_in[3];
    const float* b1l  = (const float*)d_in[4];
    const float* w1r  = (const float*)d_in[5];
    const float* w2l  = (const float*)d_in[6];
    const float* b2l  = (const float*)d_in[7];
    const float* w2r  = (const float*)d_in[8];
    const float* w3l  = (const float*)d_in[9];
    const float* b3l  = (const float*)d_in[10];
    const float* w3r  = (const float*)d_in[11];
    const float* bn1g = (const float*)d_in[12];
    const float* bn1b = (const float*)d_in[13];
    const float* bn1m = (const float*)d_in[14];
    const float* bn1v = (const float*)d_in[15];
    const float* bn2g = (const float*)d_in[16];
    const float* bn2b = (const float*)d_in[17];
    const float* bn2m = (const float*)d_in[18];
    const float* bn2v = (const float*)d_in[19];
    const float* dw1  = (const float*)d_in[20];
    const float* db1  = (const float*)d_in[21];
    const float* dw2  = (const float*)d_in[22];
    const float* db2  = (const float*)d_in[23];
    float* out = (float*)d_out;

    const int N = in_sizes[0] / 256;
    const int E = in_sizes[1] / 2;
    const int L = in_sizes[2] / 2;
    const int* src = ei;
    const int* dst = ei + E;
    const int ntiles = (N + 1023) >> 10;
    const int nblk = (N + 127) / 128;
    const int Npad = nblk * 128;

    char* wsb = (char*)d_ws;
    size_t off = 0;
    auto carve = [&](size_t bytes) -> void* {
        void* p = wsb + off;
        off += (bytes + 255) & ~(size_t)255;
        return p;
    };
    int* ptr        = (int*)carve((size_t)(N + 1) * 4);
    int* cursor     = (int*)carve((size_t)N * 4);
    int* tilesum    = (int*)carve((size_t)ntiles * 4);
    int* edges      = (int*)carve((size_t)E * 4);
    ushort* WS1     = (ushort*)carve((size_t)256 * 768 * 2);
    ushort* WS2     = (ushort*)carve((size_t)256 * 384 * 2);
    ushort* WS3     = (ushort*)carve((size_t)256 * 384 * 2);
    ushort* WS4     = (ushort*)carve((size_t)256 * 384 * 2);
    float* tl_c     = (float*)carve((size_t)N * 128 * 4);    // neighbor-transform
    float* tr_c     = (float*)carve((size_t)N * 128 * 4);    // root-transform
    ushort* A3      = (ushort*)carve((size_t)Npad * 512 * 2); // layer-1 [hi|lo]
    ushort* h3      = A3;                                     // reuse: [Npad][256]

    // ---- CSR build ----
    hipMemsetAsync(cursor, 0, (size_t)N * 4, stream);
    count_kernel<<<(E + 255) / 256, 256, 0, stream>>>(dst, cursor, E);
    scanA_kernel<<<ntiles, 1024, 0, stream>>>(cursor, ptr, tilesum, N);
    scanB_kernel<<<1, 64, 0, stream>>>(tilesum, ptr, ntiles, N);
    scanC_kernel<<<(N + 255) / 256, 256, 0, stream>>>(ptr, tilesum, N);
    hipMemsetAsync(cursor, 0, (size_t)N * 4, stream);
    scatter_kernel<<<(E + 255) / 256, 256, 0, stream>>>(src, dst, ptr, cursor, edges, E);

    // ---- conversions ----
    convx_kernel<<<(N * 64 + 255) / 256, 256, 0, stream>>>(x, A3, N * 64);
    wprep_all_kernel<<<dim3(256, 4), 256, 0, stream>>>(w1l, w1r, w2l, w2r, w3l, w3r,
                                                       dw1, WS1, WS2, WS3, WS4);

    // ---- layer 1 ----
    mm_kernel<512><<<nblk * 2, 256, 0, stream>>>(A3, WS1, tl_c, tr_c, N);
    agg_kernel<<<(N + 3) / 4, 256, 0, stream>>>(tl_c, tr_c, ptr, edges, b1l,
                                                bn1g, bn1b, bn1m, bn1v, 1, h3, N);
    // ---- layer 2 ----
    mm_kernel<256><<<nblk * 2, 256, 0, stream>>>(h3, WS2, tl_c, tr_c, N);
    agg_kernel<<<(N + 3) / 4, 256, 0, stream>>>(tl_c, tr_c, ptr, edges, b2l,
                                                bn2g, bn2b, bn2m, bn2v, 1, h3, N);
    // ---- layer 3 (no BN) ----
    mm_kernel<256><<<nblk * 2, 256, 0, stream>>>(h3, WS3, tl_c, tr_c, N);
    agg_kernel<<<(N + 3) / 4, 256, 0, stream>>>(tl_c, tr_c, ptr, edges, b3l,
                                                bn1g, bn1b, bn1m, bn1v, 0, h3, N);
    // ---- decoder transforms u|v, then pair decode ----
    mm_kernel<256><<<nblk * 2, 256, 0, stream>>>(h3, WS4, tl_c, tr_c, N);
    decode_kernel<<<(L + 255) / 256, 256, 0, stream>>>(tl_c, tr_c, eli, db1, dw2, db2, out, L);
}

// Round 8
// 392.240 us; speedup vs baseline: 1.2010x; 1.2010x over previous
//
#include <hip/hip_runtime.h>
#include <hip/hip_fp16.h>

// ---------------------------------------------------------------------------
// GraphSAGE (3x SAGEConv mean-agg + BN/ReLU) + link decoder.
// R8 changes vs R7:
//  - mm: REVERTED to R6 single-phase 128x256 structure (R7's col-split+2phase
//    regressed: doubled A staging + 2x barriers).
//  - fp16 value pathway for all RANDOM-GATHERED data: mm writes tl (agg
//    neighbor input) and both decoder operands as fp16 (2^-11 rel, analyzed
//    ~+5e-4 final absmax); streamed root tr stays f32; GEMM inputs keep the
//    bf16 hi/lo split (2^-17). Gather bytes halve: agg 410->205MB logical.
// ---------------------------------------------------------------------------

typedef unsigned int uint;
using s16x8 = __attribute__((ext_vector_type(8))) short;
using f32x4 = __attribute__((ext_vector_type(4))) float;

__device__ inline void bsplit(float v, ushort& hi, ushort& lo) {
    // round-to-nearest-even bf16 split: v ~= hi + lo to ~2^-17 rel
    uint u = __float_as_uint(v);
    uint hb = (u + 0x7FFFu + ((u >> 16) & 1u)) >> 16;
    hi = (ushort)hb;
    float r = v - __uint_as_float(hb << 16);
    uint u2 = __float_as_uint(r);
    lo = (ushort)((u2 + 0x7FFFu + ((u2 >> 16) & 1u)) >> 16);
}

__device__ inline ushort f2h(float v) { return __half_as_ushort(__float2half(v)); }

__device__ inline float4 h4f(uint2 r) {
    float2 fa = __half22float2(*(const __half2*)&r.x);
    float2 fb = __half22float2(*(const __half2*)&r.y);
    return make_float4(fa.x, fa.y, fb.x, fb.y);
}

// swizzle a ushort index within its 64-ushort K-slice: chunk ^= (row&7)
__device__ inline uint swz(uint i, uint r) {
    return (i & ~63u) | ((i ^ (r << 3)) & 56u) | (i & 7u);
}

// async global->LDS, 16 bytes per lane
__device__ inline void gload16(const void* g, void* l) {
    __builtin_amdgcn_global_load_lds(
        (const __attribute__((address_space(1))) unsigned int*)g,
        (__attribute__((address_space(3))) unsigned int*)l, 16, 0, 0);
}

// ---------------- CSR build ----------------
__global__ void count_kernel(const int* __restrict__ dst, int* __restrict__ cnt, int E) {
    int i = blockIdx.x * blockDim.x + threadIdx.x;
    if (i < E) atomicAdd(&cnt[dst[i]], 1);
}

__global__ void scanA_kernel(const int* __restrict__ cnt, int* __restrict__ ptr,
                             int* __restrict__ tilesum, int n) {
    __shared__ int sd[1024];
    int t = threadIdx.x;
    int i = blockIdx.x * 1024 + t;
    int v = (i < n) ? cnt[i] : 0;
    sd[t] = v;
    __syncthreads();
    #pragma unroll
    for (int off = 1; off < 1024; off <<= 1) {
        int add = (t >= off) ? sd[t - off] : 0;
        __syncthreads();
        sd[t] += add;
        __syncthreads();
    }
    if (i < n) ptr[i] = sd[t] - v;              // local exclusive
    if (t == 1023) tilesum[blockIdx.x] = sd[t]; // tile total
}

__global__ void scanB_kernel(int* __restrict__ tilesum, int* __restrict__ ptr,
                             int ntiles, int n) {
    if (threadIdx.x == 0 && blockIdx.x == 0) {
        int running = 0;
        for (int b = 0; b < ntiles; ++b) {
            int t = tilesum[b];
            tilesum[b] = running;
            running += t;
        }
        ptr[n] = running;
    }
}

__global__ void scanC_kernel(int* __restrict__ ptr, const int* __restrict__ tilesum, int n) {
    int i = blockIdx.x * blockDim.x + threadIdx.x;
    if (i < n) ptr[i] += tilesum[i >> 10];
}

__global__ void scatter_kernel(const int* __restrict__ src, const int* __restrict__ dst,
                               const int* __restrict__ ptr, int* __restrict__ cursor,
                               int* __restrict__ edges, int E) {
    int i = blockIdx.x * blockDim.x + threadIdx.x;
    if (i < E) {
        int d = dst[i];
        int pos = ptr[d] + atomicAdd(&cursor[d], 1);
        edges[pos] = src[i];
    }
}

// ---------------- conversions (pre-swizzled stores) ----------------
// A row (K=256): [hi(0..255) | lo(0..255)] (KP=512), chunk-swizzled per slice
__global__ __launch_bounds__(256) void convx_kernel(const float* __restrict__ x,
                                                    ushort* __restrict__ A3, int total) {
    int e = blockIdx.x * 256 + threadIdx.x;   // total = N*64 (float4 groups)
    if (e >= total) return;
    uint row = e >> 6;
    uint k4 = (e & 63) << 2;
    float4 v = *(const float4*)(x + (size_t)row * 256 + k4);
    ushort4 hi, lo;
    bsplit(v.x, hi.x, lo.x); bsplit(v.y, hi.y, lo.y);
    bsplit(v.z, hi.z, lo.z); bsplit(v.w, hi.w, lo.w);
    ushort* d = A3 + (size_t)row * 512;
    *(ushort4*)(d + swz(k4, row))       = hi;
    *(ushort4*)(d + swz(k4 + 256, row)) = lo;
}

// WS[n][k'] n-major, k' = [Wh | Wlo | Wh], chunk-swizzled per slice
__global__ void wprep_all_kernel(
    const float* __restrict__ w1l, const float* __restrict__ w1r,
    const float* __restrict__ w2l, const float* __restrict__ w2r,
    const float* __restrict__ w3l, const float* __restrict__ w3r,
    const float* __restrict__ dw1,
    ushort* __restrict__ WS1, ushort* __restrict__ WS2,
    ushort* __restrict__ WS3, ushort* __restrict__ WS4)
{
    int which = blockIdx.y;
    uint n = blockIdx.x;
    uint k = threadIdx.x;
    const float *wa, *wb;
    uint K, lda, aoff, boff;
    ushort* WS;
    switch (which) {
        case 0:  wa = w1l; wb = w1r; K = 256; lda = 256; aoff = 0; boff = 0;   WS = WS1; break;
        case 1:  wa = w2l; wb = w2r; K = 128; lda = 128; aoff = 0; boff = 0;   WS = WS2; break;
        case 2:  wa = w3l; wb = w3r; K = 128; lda = 128; aoff = 0; boff = 0;   WS = WS3; break;
        default: wa = dw1; wb = dw1; K = 128; lda = 256; aoff = 0; boff = 128; WS = WS4; break;
    }
    if (k >= K) return;
    const float* srcr = (n < 128) ? (wa + (size_t)n * lda + aoff)
                                  : (wb + (size_t)(n - 128) * lda + boff);
    ushort hi, lo;
    bsplit(srcr[k], hi, lo);
    ushort* d = WS + (size_t)n * 3 * K;
    d[swz(k, n)]         = hi;
    d[swz(K + k, n)]     = lo;
    d[swz(2 * K + k, n)] = hi;
}

// ---------------- MFMA GEMM (R6 structure) ----------------
// Block = 128 rows x 256 cols. 4 waves, each 64x128.
// A[M][KP] = [hi|lo] pre-swizzled; W[256][KP*3/2] = [Wh|Wlo|Wh] pre-swizzled.
// Staging = global_load_lds 16B into LINEAR LDS; ds_read applies the XOR.
// Cl (cols 0..127) written fp16; Cr written fp16 iff CRF16 else f32.
template <int KP, int CRF16>
__global__ __launch_bounds__(256, 2) void mm_kernel(const ushort* __restrict__ A,
                                                    const ushort* __restrict__ WS,
                                                    ushort* __restrict__ Cl,
                                                    void* __restrict__ Cr_, int M) {
    constexpr int KS  = (KP / 64) + (KP / 128);   // 12 (KP=512) or 6 (KP=256)
    constexpr int WKP = KP + KP / 2;
    __shared__ ushort At[128 * 64];
    __shared__ ushort Bt[256 * 64];
    const int t = threadIdx.x;
    const int lane = t & 63;
    const int wave = t >> 6;
    const int wm = wave >> 1, wn = wave & 1;      // 2 row-halves x 2 col-halves
    const int row0 = blockIdx.x * 128;
    const int l15 = lane & 15;
    const int l4 = lane >> 4;
    const int l8 = lane >> 3;                     // staging row within 8-row group
    const int c8 = lane & 7;                      // staging chunk within row

    f32x4 acc[4][8] = {};

    for (int s = 0; s < KS; ++s) {
        const int as = (s < KP / 128) ? s : s - (KP / 128);
        #pragma unroll
        for (int j = 0; j < 4; ++j) {
            int jj = wave + j * 4;                // A group 0..15
            int r = jj * 8 + l8;
            gload16(A + (size_t)(row0 + r) * KP + as * 64 + c8 * 8,
                    (char*)At + jj * 1024 + lane * 16);
        }
        #pragma unroll
        for (int j = 0; j < 8; ++j) {
            int jj = wave + j * 4;                // B group 0..31
            int r = jj * 8 + l8;
            gload16(WS + (size_t)r * WKP + s * 64 + c8 * 8,
                    (char*)Bt + jj * 1024 + lane * 16);
        }
        __syncthreads();
        #pragma unroll
        for (int kk = 0; kk < 64; kk += 32) {
            s16x8 af[4], bf[8];
            #pragma unroll
            for (int mi = 0; mi < 4; ++mi) {
                int r = wm * 64 + mi * 16 + l15;
                int off = (kk + l4 * 8) ^ ((r & 7) * 8);
                af[mi] = *(const s16x8*)&At[r * 64 + off];
            }
            #pragma unroll
            for (int ni = 0; ni < 8; ++ni) {
                int r = wn * 128 + ni * 16 + l15;
                int off = (kk + l4 * 8) ^ ((r & 7) * 8);
                bf[ni] = *(const s16x8*)&Bt[r * 64 + off];
            }
            #pragma unroll
            for (int mi = 0; mi < 4; ++mi)
                #pragma unroll
                for (int ni = 0; ni < 8; ++ni)
                    acc[mi][ni] = __builtin_amdgcn_mfma_f32_16x16x32_bf16(
                        af[mi], bf[ni], acc[mi][ni], 0, 0, 0);
        }
        __syncthreads();
    }
    // ---- epilogue: row = (lane>>4)*4+j, col = lane&15 within 16x16
    #pragma unroll
    for (int mi = 0; mi < 4; ++mi) {
        int rbase = row0 + wm * 64 + mi * 16 + l4 * 4;
        #pragma unroll
        for (int ni = 0; ni < 8; ++ni) {
            int col = ni * 16 + l15;
            #pragma unroll
            for (int j = 0; j < 4; ++j) {
                int r = rbase + j;
                if (r < M) {
                    if (wn == 0) {
                        Cl[(size_t)r * 128 + col] = f2h(acc[mi][ni][j]);
                    } else if (CRF16) {
                        ((ushort*)Cr_)[(size_t)r * 128 + col] = f2h(acc[mi][ni][j]);
                    } else {
                        ((float*)Cr_)[(size_t)r * 128 + col] = acc[mi][ni][j];
                    }
                }
            }
        }
    }
}

// ---------------- aggregation ----------------
// One node per wave; lanes 0-31 even edge slots, 32-63 odd; shfl_xor combine.
// tl is fp16 (256B/row gathers); root tr is f32 (streamed).
// out = opt_bn_relu( mean tl[src] + bl + tr[i] ), emits h[n][256]=[hi|lo] swz.
__global__ __launch_bounds__(256, 4) void agg_kernel(
    const ushort* __restrict__ tl, const float* __restrict__ tr,
    const int* __restrict__ ptr, const int* __restrict__ edges,
    const float* __restrict__ bl,
    const float* __restrict__ bng, const float* __restrict__ bnb,
    const float* __restrict__ bnm, const float* __restrict__ bnv,
    int do_bn, ushort* __restrict__ h3, int n) {
    const int wave = threadIdx.x >> 6;
    const int lane = threadIdx.x & 63;
    const uint node = blockIdx.x * 4 + wave;
    if (node >= (uint)n) return;
    const int half = lane >> 5;
    const uint q4 = (lane & 31) << 2;             // 4 feats per lane
    const int p0 = ptr[node], p1 = ptr[node + 1];
    float4 a0 = make_float4(0.f, 0.f, 0.f, 0.f), a1 = a0, a2 = a0, a3 = a0;
    float4 a4 = a0, a5 = a0, a6 = a0, a7 = a0;
    int e = p0 + half;
    for (; e + 14 < p1; e += 16) {                // 8 edges per half per iter
        int i0 = edges[e],      i1 = edges[e + 2],  i2 = edges[e + 4],  i3 = edges[e + 6];
        int i4 = edges[e + 8],  i5 = edges[e + 10], i6 = edges[e + 12], i7 = edges[e + 14];
        uint2 r0 = *(const uint2*)(tl + (size_t)i0 * 128 + q4);
        uint2 r1 = *(const uint2*)(tl + (size_t)i1 * 128 + q4);
        uint2 r2 = *(const uint2*)(tl + (size_t)i2 * 128 + q4);
        uint2 r3 = *(const uint2*)(tl + (size_t)i3 * 128 + q4);
        uint2 r4 = *(const uint2*)(tl + (size_t)i4 * 128 + q4);
        uint2 r5 = *(const uint2*)(tl + (size_t)i5 * 128 + q4);
        uint2 r6 = *(const uint2*)(tl + (size_t)i6 * 128 + q4);
        uint2 r7 = *(const uint2*)(tl + (size_t)i7 * 128 + q4);
        float4 v0 = h4f(r0), v1 = h4f(r1), v2 = h4f(r2), v3 = h4f(r3);
        float4 v4 = h4f(r4), v5 = h4f(r5), v6 = h4f(r6), v7 = h4f(r7);
        a0.x += v0.x; a0.y += v0.y; a0.z += v0.z; a0.w += v0.w;
        a1.x += v1.x; a1.y += v1.y; a1.z += v1.z; a1.w += v1.w;
        a2.x += v2.x; a2.y += v2.y; a2.z += v2.z; a2.w += v2.w;
        a3.x += v3.x; a3.y += v3.y; a3.z += v3.z; a3.w += v3.w;
        a4.x += v4.x; a4.y += v4.y; a4.z += v4.z; a4.w += v4.w;
        a5.x += v5.x; a5.y += v5.y; a5.z += v5.z; a5.w += v5.w;
        a6.x += v6.x; a6.y += v6.y; a6.z += v6.z; a6.w += v6.w;
        a7.x += v7.x; a7.y += v7.y; a7.z += v7.z; a7.w += v7.w;
    }
    for (; e < p1; e += 2) {
        int i0 = edges[e];
        float4 v0 = h4f(*(const uint2*)(tl + (size_t)i0 * 128 + q4));
        a0.x += v0.x; a0.y += v0.y; a0.z += v0.z; a0.w += v0.w;
    }
    float4 s;
    s.x = ((a0.x + a1.x) + (a2.x + a3.x)) + ((a4.x + a5.x) + (a6.x + a7.x));
    s.y = ((a0.y + a1.y) + (a2.y + a3.y)) + ((a4.y + a5.y) + (a6.y + a7.y));
    s.z = ((a0.z + a1.z) + (a2.z + a3.z)) + ((a4.z + a5.z) + (a6.z + a7.z));
    s.w = ((a0.w + a1.w) + (a2.w + a3.w)) + ((a4.w + a5.w) + (a6.w + a7.w));
    // combine even/odd halves (lane <-> lane^32)
    s.x += __shfl_xor(s.x, 32);
    s.y += __shfl_xor(s.y, 32);
    s.z += __shfl_xor(s.z, 32);
    s.w += __shfl_xor(s.w, 32);
    if (half == 0) {
        float inv = 1.f / fmaxf((float)(p1 - p0), 1.f);
        float4 r = *(const float4*)(tr + (size_t)node * 128 + q4);
        float4 b = *(const float4*)(bl + q4);
        float4 val;
        val.x = fmaf(s.x, inv, b.x) + r.x;
        val.y = fmaf(s.y, inv, b.y) + r.y;
        val.z = fmaf(s.z, inv, b.z) + r.z;
        val.w = fmaf(s.w, inv, b.w) + r.w;
        if (do_bn) {
            float4 g = *(const float4*)(bng + q4);
            float4 be = *(const float4*)(bnb + q4);
            float4 m = *(const float4*)(bnm + q4);
            float4 vv = *(const float4*)(bnv + q4);
            val.x = fmaxf(fmaf(val.x - m.x, g.x * rsqrtf(vv.x + 1e-5f), be.x), 0.f);
            val.y = fmaxf(fmaf(val.y - m.y, g.y * rsqrtf(vv.y + 1e-5f), be.y), 0.f);
            val.z = fmaxf(fmaf(val.z - m.z, g.z * rsqrtf(vv.z + 1e-5f), be.z), 0.f);
            val.w = fmaxf(fmaf(val.w - m.w, g.w * rsqrtf(vv.w + 1e-5f), be.w), 0.f);
        }
        ushort4 hi, lo;
        bsplit(val.x, hi.x, lo.x); bsplit(val.y, hi.y, lo.y);
        bsplit(val.z, hi.z, lo.z); bsplit(val.w, hi.w, lo.w);
        ushort* d = h3 + (size_t)node * 256;
        *(ushort4*)(d + swz(q4, node))       = hi;
        *(ushort4*)(d + swz(q4 + 128, node)) = lo;
    }
}

// ---------------- decoder: relu(u[s] + v[d] + b) . w2 + b2 (u,v fp16) -------
__global__ __launch_bounds__(256) void decode_kernel(
    const ushort* __restrict__ u, const ushort* __restrict__ v,
    const int* __restrict__ eli, const float* __restrict__ db1,
    const float* __restrict__ dw2, const float* __restrict__ db2,
    float* __restrict__ out, int L) {
    __shared__ float sb[128], sw[128];
    if (threadIdx.x < 128) {
        sb[threadIdx.x] = db1[threadIdx.x];
        sw[threadIdx.x] = dw2[threadIdx.x];
    }
    __syncthreads();
    int p = blockIdx.x * 256 + threadIdx.x;
    if (p >= L) return;
    int s = eli[p], d = eli[L + p];
    const ushort* up = u + (size_t)s * 128;
    const ushort* vp = v + (size_t)d * 128;
    float acc = db2[0];
    #pragma unroll 8
    for (int o = 0; o < 128; o += 4) {
        float4 a = h4f(*(const uint2*)(up + o));
        float4 b = h4f(*(const uint2*)(vp + o));
        float4 bb = *(const float4*)(&sb[o]);
        float4 w = *(const float4*)(&sw[o]);
        acc += fmaxf(a.x + b.x + bb.x, 0.f) * w.x;
        acc += fmaxf(a.y + b.y + bb.y, 0.f) * w.y;
        acc += fmaxf(a.z + b.z + bb.z, 0.f) * w.z;
        acc += fmaxf(a.w + b.w + bb.w, 0.f) * w.w;
    }
    out[p] = acc;
}

extern "C" void kernel_launch(void* const* d_in, const int* in_sizes, int n_in,
                              void* d_out, int out_size, void* d_ws, size_t ws_size,
                              hipStream_t stream) {
    const float* x    = (const float*)d_in[0];
    const int*   ei   = (const int*)d_in[1];
    const int*   eli  = (const int*)d_in[2];
    const float* w1l  = (const float*)d_in[3];
    const float* b1l  = (const float*)d_in[4];
    const float* w1r  = (const float*)d_in[5];
    const float* w2l  = (const float*)d_in[6];
    const float* b2l  = (const float*)d_in[7];
    const float* w2r  = (const float*)d_in[8];
    const float* w3l  = (const float*)d_in[9];
    const float* b3l  = (const float*)d_in[10];
    const float* w3r  = (const float*)d_in[11];
    const float* bn1g = (const float*)d_in[12];
    const float* bn1b = (const float*)d_in[13];
    const float* bn1m = (const float*)d_in[14];
    const float* bn1v = (const float*)d_in[15];
    const float* bn2g = (const float*)d_in[16];
    const float* bn2b = (const float*)d_in[17];
    const float* bn2m = (const float*)d_in[18];
    const float* bn2v = (const float*)d_in[19];
    const float* dw1  = (const float*)d_in[20];
    const float* db1  = (const float*)d_in[21];
    const float* dw2  = (const float*)d_in[22];
    const float* db2  = (const float*)d_in[23];
    float* out = (float*)d_out;

    const int N = in_sizes[0] / 256;
    const int E = in_sizes[1] / 2;
    const int L = in_sizes[2] / 2;
    const int* src = ei;
    const int* dst = ei + E;
    const int ntiles = (N + 1023) >> 10;
    const int nblk = (N + 127) / 128;
    const int Npad = nblk * 128;

    char* wsb = (char*)d_ws;
    size_t off = 0;
    auto carve = [&](size_t bytes) -> void* {
        void* p = wsb + off;
        off += (bytes + 255) & ~(size_t)255;
        return p;
    };
    int* ptr        = (int*)carve((size_t)(N + 1) * 4);
    int* cursor     = (int*)carve((size_t)N * 4);
    int* tilesum    = (int*)carve((size_t)ntiles * 4);
    int* edges      = (int*)carve((size_t)E * 4);
    ushort* WS1     = (ushort*)carve((size_t)256 * 768 * 2);
    ushort* WS2     = (ushort*)carve((size_t)256 * 384 * 2);
    ushort* WS3     = (ushort*)carve((size_t)256 * 384 * 2);
    ushort* WS4     = (ushort*)carve((size_t)256 * 384 * 2);
    ushort* tl_h    = (ushort*)carve((size_t)N * 128 * 2);   // neighbor-transform (fp16)
    float* tr_c     = (float*)carve((size_t)N * 128 * 4);    // root-transform (f32) / dec-v (fp16)
    ushort* A3      = (ushort*)carve((size_t)Npad * 512 * 2); // layer-1 [hi|lo]
    ushort* h3      = A3;                                     // reuse: [Npad][256]

    // ---- CSR build ----
    hipMemsetAsync(cursor, 0, (size_t)N * 4, stream);
    count_kernel<<<(E + 255) / 256, 256, 0, stream>>>(dst, cursor, E);
    scanA_kernel<<<ntiles, 1024, 0, stream>>>(cursor, ptr, tilesum, N);
    scanB_kernel<<<1, 64, 0, stream>>>(tilesum, ptr, ntiles, N);
    scanC_kernel<<<(N + 255) / 256, 256, 0, stream>>>(ptr, tilesum, N);
    hipMemsetAsync(cursor, 0, (size_t)N * 4, stream);
    scatter_kernel<<<(E + 255) / 256, 256, 0, stream>>>(src, dst, ptr, cursor, edges, E);

    // ---- conversions ----
    convx_kernel<<<(N * 64 + 255) / 256, 256, 0, stream>>>(x, A3, N * 64);
    wprep_all_kernel<<<dim3(256, 4), 256, 0, stream>>>(w1l, w1r, w2l, w2r, w3l, w3r,
                                                       dw1, WS1, WS2, WS3, WS4);

    // ---- layer 1 ----
    mm_kernel<512, 0><<<nblk, 256, 0, stream>>>(A3, WS1, tl_h, tr_c, N);
    agg_kernel<<<(N + 3) / 4, 256, 0, stream>>>(tl_h, tr_c, ptr, edges, b1l,
                                                bn1g, bn1b, bn1m, bn1v, 1, h3, N);
    // ---- layer 2 ----
    mm_kernel<256, 0><<<nblk, 256, 0, stream>>>(h3, WS2, tl_h, tr_c, N);
    agg_kernel<<<(N + 3) / 4, 256, 0, stream>>>(tl_h, tr_c, ptr, edges, b2l,
                                                bn2g, bn2b, bn2m, bn2v, 1, h3, N);
    // ---- layer 3 (no BN) ----
    mm_kernel<256, 0><<<nblk, 256, 0, stream>>>(h3, WS3, tl_h, tr_c, N);
    agg_kernel<<<(N + 3) / 4, 256, 0, stream>>>(tl_h, tr_c, ptr, edges, b3l,
                                                bn1g, bn1b, bn1m, bn1v, 0, h3, N);
    // ---- decoder transforms u|v (both fp16), then pair decode ----
    mm_kernel<256, 1><<<nblk, 256, 0, stream>>>(h3, WS4, tl_h, tr_c, N);
    decode_kernel<<<(L + 255) / 256, 256, 0, stream>>>(tl_h, (const ushort*)tr_c, eli,
                                                       db1, dw2, db2, out, L);
}